// Round 4
// baseline (35.091 us; speedup 1.0000x reference)
//
#include <hip/hip_runtime.h>
#include <hip/hip_bf16.h>

#define S 1024
#define BPB 8     // blocks per batch
#define BLK 256   // 4 waves

// hinge = relu(1 - sign(l_i - l_j)*(p_i - p_j)); tie (dl==0) -> 1.
__device__ __forceinline__ float pair_term(float pi, float li, float pj, float lj) {
  float dp = pi - pj;
  float dl = li - lj;
  unsigned sx = __float_as_uint(dl) & 0x80000000u;
  float x = __uint_as_float(__float_as_uint(dp) ^ sx);  // sign(dl)*dp for dl!=0
  float h = fmaxf(1.0f - x, 0.0f);
  return (dl == 0.0f) ? 1.0f : h;
}

// Fused kernel: 8 blocks per batch; block k owns j-tile pair {t,3-t} (t=k&1
// ? 1 : 0 mapped below), each wave holds 4 j's per tile in registers and
// broadcasts i from LDS via b128 (2 i's/read, serves 8 reg-pairs).
// Wave chunk c = (k>>1)*4 + wave owns i-chunk c/16 of each tile's i-range.
// Last block (ticket) finalizes: per-batch /len^2, global sum, /total_sents.
__global__ __launch_bounds__(BLK) void rank_loss_kernel(
    const float* __restrict__ preds,
    const float* __restrict__ labels,
    const int* __restrict__ lens,
    float* __restrict__ out,
    float* __restrict__ partial,
    unsigned int* __restrict__ counter,
    int B, int nblocks) {
  const int bid = blockIdx.x;
  const int b = bid >> 3;
  const int k = bid & 7;

  __shared__ float2 pl[S];
  __shared__ float msk[S];
  __shared__ float wsum[BLK / 64];
  __shared__ int lastflag;

  const float* pr = preds + (size_t)b * S;
  const float* lr = labels + (size_t)b * S;
  {
    const float4 pv = ((const float4*)pr)[threadIdx.x];
    const float4 lv = ((const float4*)lr)[threadIdx.x];
    const float pm[4] = {pv.x, pv.y, pv.z, pv.w};
    const float lm[4] = {lv.x, lv.y, lv.z, lv.w};
#pragma unroll
    for (int e = 0; e < 4; ++e) {
      float m = (lm[e] != -1.0f) ? 1.0f : 0.0f;
      pl[threadIdx.x * 4 + e] = make_float2(pm[e] * m, lm[e] * m);
      msk[threadIdx.x * 4 + e] = m;
    }
  }
  __syncthreads();

  const int wv = threadIdx.x >> 6;
  const int lane = threadIdx.x & 63;
  const int g = k & 1;                 // tile-pair group
  const int c = (k >> 1) * 4 + wv;     // i-chunk 0..15
  const float4* pl4 = (const float4*)pl;

  float wacc = 0.0f;

#pragma unroll
  for (int ti = 0; ti < 2; ++ti) {
    const int jt = ti ? (3 - g) : g;   // g=0 -> {0,3}, g=1 -> {1,2}
    const int jbase = jt * 256;
    float pj[4], lj[4], mj[4];
#pragma unroll
    for (int r = 0; r < 4; ++r) {
      int j = jbase + r * 64 + lane;
      float2 v = pl[j];
      pj[r] = v.x; lj[r] = v.y; mj[r] = msk[j];
    }
    const int clen = (jbase + 256) >> 4;   // 16*(jt+1)
    const int lo = c * clen, hi = lo + clen;
    const int zs = jbase;                  // diagonal zone start
    float acc[4] = {0.f, 0.f, 0.f, 0.f};

    // Uniform region: all i < jbase -> every reg valid.
    const int uhi = hi < zs ? hi : zs;
    for (int i = lo; i < uhi; i += 2) {
      float4 q = pl4[i >> 1];
#pragma unroll
      for (int r = 0; r < 4; ++r) {
        acc[r] += pair_term(q.x, q.y, pj[r], lj[r]);
        acc[r] += pair_term(q.z, q.w, pj[r], lj[r]);
      }
    }
    // Zone region: per-reg wave-uniform guards; per-lane predication only
    // inside each reg's 64-wide diagonal block.
    const int plo = lo > zs ? lo : zs;
    for (int i = plo; i < hi; i += 2) {
      float4 q = pl4[i >> 1];
#pragma unroll
      for (int r = 0; r < 4; ++r) {
        const int jb = jbase + r * 64;     // lane-0 j of reg r
        if (i + 2 <= jb) {                 // uniform-valid (scalar branch)
          acc[r] += pair_term(q.x, q.y, pj[r], lj[r]);
          acc[r] += pair_term(q.z, q.w, pj[r], lj[r]);
        } else if (i < jb + 64) {          // diagonal block: predicate i<j
          const int j = jb + lane;
          float ta = (i     < j) ? pair_term(q.x, q.y, pj[r], lj[r]) : 0.0f;
          float tb = (i + 1 < j) ? pair_term(q.z, q.w, pj[r], lj[r]) : 0.0f;
          acc[r] += ta + tb;
        }                                   // else: fully above diagonal, skip
      }
    }
#pragma unroll
    for (int r = 0; r < 4; ++r) wacc = fmaf(acc[r], mj[r], wacc);
  }

  // Deterministic block reduction.
  for (int off = 32; off > 0; off >>= 1)
    wacc += __shfl_down(wacc, off, 64);
  if (lane == 0) wsum[wv] = wacc;
  __syncthreads();
  if (threadIdx.x == 0) {
    float tot = 0.0f;
#pragma unroll
    for (int w = 0; w < BLK / 64; ++w) tot += wsum[w];
    partial[bid] = tot;
    __threadfence();
    unsigned int old = atomicAdd(counter, 1u);
    lastflag = (old == (unsigned int)(nblocks - 1)) ? 1 : 0;
  }
  __syncthreads();

  // Last block finalizes (deterministic fixed-order reduction).
  if (lastflag && threadIdx.x < 64) {
    __threadfence();
    const int bb = threadIdx.x;
    float norm = 0.0f, sents = 0.0f;
    if (bb < B) {
      float s = 0.0f;
#pragma unroll
      for (int kk = 0; kk < BPB; ++kk)
        s += ((volatile const float*)partial)[bb * BPB + kk];
      float len = (float)lens[bb];
      norm = s / (len * len);
      sents = (lens[bb] != 0) ? 1.0f : 0.0f;
    }
    for (int off = 32; off > 0; off >>= 1) {
      norm  += __shfl_down(norm, off, 64);
      sents += __shfl_down(sents, off, 64);
    }
    if (threadIdx.x == 0) {
      out[0] = norm / sents;
      out[1] = sents;
    }
  }
}

extern "C" void kernel_launch(void* const* d_in, const int* in_sizes, int n_in,
                              void* d_out, int out_size, void* d_ws, size_t ws_size,
                              hipStream_t stream) {
  const float* preds  = (const float*)d_in[0];
  const float* labels = (const float*)d_in[1];
  const int*   lens   = (const int*)d_in[2];
  float* out = (float*)d_out;

  const int B = in_sizes[2];                  // 64
  const int nblocks = B * BPB;                // 512

  unsigned int* counter = (unsigned int*)d_ws;            // 4 B at offset 0
  float* partial = (float*)((char*)d_ws + 256);           // nblocks floats

  hipMemsetAsync(d_ws, 0, 4, stream);         // zero ticket counter (capture-legal)
  rank_loss_kernel<<<dim3(nblocks), dim3(BLK), 0, stream>>>(
      preds, labels, lens, out, partial, counter, B, nblocks);
}

// Round 5
// 23.383 us; speedup vs baseline: 1.5007x; 1.5007x over previous
//
#include <hip/hip_runtime.h>
#include <hip/hip_bf16.h>

#define S 1024
#define BPB 8     // blocks per batch
#define BLK 256   // 4 waves

// hinge = relu(1 - sign(l_i - l_j)*(p_i - p_j)); tie (dl==0) -> 1.
__device__ __forceinline__ float pair_term(float pi, float li, float pj, float lj) {
  float dp = pi - pj;
  float dl = li - lj;
  unsigned sx = __float_as_uint(dl) & 0x80000000u;
  float x = __uint_as_float(__float_as_uint(dp) ^ sx);  // sign(dl)*dp for dl!=0
  float h = fmaxf(1.0f - x, 0.0f);
  return (dl == 0.0f) ? 1.0f : h;
}

// Kernel 1: block k of batch b owns j-tile pair {g, 3-g} (256-wide tiles,
// 4 j-regs per lane); waves split the i-range into 16 chunks; i is broadcast
// from LDS via b128 (2 i's/read serves 8 reg-pairs = 512 pair terms/read).
__global__ __launch_bounds__(BLK) void rank_partial_kernel(
    const float* __restrict__ preds,
    const float* __restrict__ labels,
    float* __restrict__ partial) {
  const int bid = blockIdx.x;
  const int b = bid >> 3;
  const int k = bid & 7;

  __shared__ float2 pl[S];
  __shared__ float msk[S];
  __shared__ float wsum[BLK / 64];

  const float* pr = preds + (size_t)b * S;
  const float* lr = labels + (size_t)b * S;
  {
    const float4 pv = ((const float4*)pr)[threadIdx.x];
    const float4 lv = ((const float4*)lr)[threadIdx.x];
    const float pm[4] = {pv.x, pv.y, pv.z, pv.w};
    const float lm[4] = {lv.x, lv.y, lv.z, lv.w};
#pragma unroll
    for (int e = 0; e < 4; ++e) {
      float m = (lm[e] != -1.0f) ? 1.0f : 0.0f;
      pl[threadIdx.x * 4 + e] = make_float2(pm[e] * m, lm[e] * m);
      msk[threadIdx.x * 4 + e] = m;
    }
  }
  __syncthreads();

  const int wv = threadIdx.x >> 6;
  const int lane = threadIdx.x & 63;
  const int g = k & 1;                 // tile-pair group: {0,3} or {1,2}
  const int c = (k >> 1) * 4 + wv;     // i-chunk 0..15
  const float4* pl4 = (const float4*)pl;

  float wacc = 0.0f;

#pragma unroll
  for (int ti = 0; ti < 2; ++ti) {
    const int jt = ti ? (3 - g) : g;
    const int jbase = jt * 256;
    float pj[4], lj[4], mj[4];
#pragma unroll
    for (int r = 0; r < 4; ++r) {
      int j = jbase + r * 64 + lane;
      float2 v = pl[j];
      pj[r] = v.x; lj[r] = v.y; mj[r] = msk[j];
    }
    const int clen = (jbase + 256) >> 4;   // 16*(jt+1)
    const int lo = c * clen, hi = lo + clen;
    const int zs = jbase;                  // diagonal zone start
    float acc[4] = {0.f, 0.f, 0.f, 0.f};

    // Uniform region: all i < jbase -> every reg valid.
    const int uhi = hi < zs ? hi : zs;
    for (int i = lo; i < uhi; i += 2) {
      float4 q = pl4[i >> 1];
#pragma unroll
      for (int r = 0; r < 4; ++r) {
        acc[r] += pair_term(q.x, q.y, pj[r], lj[r]);
        acc[r] += pair_term(q.z, q.w, pj[r], lj[r]);
      }
    }
    // Zone region: per-reg wave-uniform guards; per-lane predication only
    // inside each reg's 64-wide diagonal block.
    const int plo = lo > zs ? lo : zs;
    for (int i = plo; i < hi; i += 2) {
      float4 q = pl4[i >> 1];
#pragma unroll
      for (int r = 0; r < 4; ++r) {
        const int jb = jbase + r * 64;     // lane-0 j of reg r
        if (i + 2 <= jb) {                 // wave-uniform valid
          acc[r] += pair_term(q.x, q.y, pj[r], lj[r]);
          acc[r] += pair_term(q.z, q.w, pj[r], lj[r]);
        } else if (i < jb + 64) {          // diagonal block: predicate i<j
          const int j = jb + lane;
          float ta = (i     < j) ? pair_term(q.x, q.y, pj[r], lj[r]) : 0.0f;
          float tb = (i + 1 < j) ? pair_term(q.z, q.w, pj[r], lj[r]) : 0.0f;
          acc[r] += ta + tb;
        }                                   // else fully above diagonal: skip
      }
    }
#pragma unroll
    for (int r = 0; r < 4; ++r) wacc = fmaf(acc[r], mj[r], wacc);
  }

  // Deterministic block reduction.
  for (int off = 32; off > 0; off >>= 1)
    wacc += __shfl_down(wacc, off, 64);
  if (lane == 0) wsum[wv] = wacc;
  __syncthreads();
  if (threadIdx.x == 0)
    partial[bid] = wsum[0] + wsum[1] + wsum[2] + wsum[3];
}

// Kernel 2: one wave finalizes (per-batch /len^2, sum over batches, /total).
__global__ __launch_bounds__(64) void rank_final_kernel(
    const float* __restrict__ partial,
    const int* __restrict__ lens,
    float* __restrict__ out,
    int B) {
  const int b = threadIdx.x;
  float norm = 0.0f, sents = 0.0f;
  if (b < B) {
    float sum = 0.0f;
#pragma unroll
    for (int s = 0; s < BPB; ++s) sum += partial[b * BPB + s];
    float len = (float)lens[b];
    norm = sum / (len * len);
    sents = (lens[b] != 0) ? 1.0f : 0.0f;
  }
  for (int off = 32; off > 0; off >>= 1) {
    norm  += __shfl_down(norm, off, 64);
    sents += __shfl_down(sents, off, 64);
  }
  if (threadIdx.x == 0) {
    out[0] = norm / sents;
    out[1] = sents;
  }
}

extern "C" void kernel_launch(void* const* d_in, const int* in_sizes, int n_in,
                              void* d_out, int out_size, void* d_ws, size_t ws_size,
                              hipStream_t stream) {
  const float* preds  = (const float*)d_in[0];
  const float* labels = (const float*)d_in[1];
  const int*   lens   = (const int*)d_in[2];
  float* out = (float*)d_out;

  const int B = in_sizes[2];                  // 64
  float* partial = (float*)d_ws;              // B * BPB floats

  rank_partial_kernel<<<dim3(B * BPB), dim3(BLK), 0, stream>>>(preds, labels, partial);
  rank_final_kernel<<<dim3(1), dim3(64), 0, stream>>>(partial, lens, out, B);
}

// Round 6
// 16.432 us; speedup vs baseline: 2.1355x; 1.4230x over previous
//
#include <hip/hip_runtime.h>
#include <hip/hip_bf16.h>

#define S 1024
#define BLK 256   // 4 waves; 8 blocks per batch -> 512 blocks, 2/CU

// hinge term: relu(1 - sign(l_i-l_j)*(p_i-p_j)); tie dl==0 -> x=0 -> term=1.
__device__ __forceinline__ float pair_term(float pi, float li, float pj, float lj) {
  float dp = pi - pj;
  float dl = li - lj;
  unsigned sx = __float_as_uint(dl) & 0x80000000u;
  float x = __uint_as_float(__float_as_uint(dp) ^ sx);  // sign(dl)*dp (dl!=0)
  x = (dl == 0.0f) ? 0.0f : x;
  return fmaxf(1.0f - x, 0.0f);
}

// Uniform region: n4 float4-iterations starting at f4lo; all 4 regs valid.
__device__ __forceinline__ void uni4(const float4* pl4, int f4lo, int n4,
                                     const float pj[4], const float lj[4],
                                     float acc[4]) {
#pragma unroll 4
  for (int t = 0; t < n4; ++t) {
    float4 q = pl4[f4lo + t];
#pragma unroll
    for (int r = 0; r < 4; ++r) {
      acc[r] += pair_term(q.x, q.y, pj[r], lj[r]);
      acc[r] += pair_term(q.z, q.w, pj[r], lj[r]);
    }
  }
}

// Staircase row R of a 256-wide group at gb: i in [gb+64R+off, +16).
// Reg R predicated (i<j), regs r>R fully valid, regs r<R excluded. Static R.
template <int R>
__device__ __forceinline__ void stair_t(const float4* pl4, int gb, int off,
                                        int lane, const float pj[4],
                                        const float lj[4], float acc[4]) {
  const int i0 = gb + 64 * R + off;
  const int j = gb + 64 * R + lane;
#pragma unroll
  for (int t = 0; t < 8; ++t) {
    float4 q = pl4[(i0 >> 1) + t];
    const int i = i0 + 2 * t;
    float ta = (i     < j) ? pair_term(q.x, q.y, pj[R], lj[R]) : 0.0f;
    float tb = (i + 1 < j) ? pair_term(q.z, q.w, pj[R], lj[R]) : 0.0f;
    acc[R] += ta + tb;
#pragma unroll
    for (int r = R + 1; r < 4; ++r) {
      acc[r] += pair_term(q.x, q.y, pj[r], lj[r]);
      acc[r] += pair_term(q.z, q.w, pj[r], lj[r]);
    }
  }
}

__device__ __forceinline__ void stair(const float4* pl4, int gb, int R, int off,
                                      int lane, const float pj[4],
                                      const float lj[4], float acc[4]) {
  switch (R) {  // wave-uniform branch
    case 0: stair_t<0>(pl4, gb, off, lane, pj, lj, acc); break;
    case 1: stair_t<1>(pl4, gb, off, lane, pj, lj, acc); break;
    case 2: stair_t<2>(pl4, gb, off, lane, pj, lj, acc); break;
    default: stair_t<3>(pl4, gb, off, lane, pj, lj, acc); break;
  }
}

// Kernel 1: batch b, block k (8/batch). P = k&1 selects group pair
// {g_lo=P, g_hi=3-P} (groups of 4 j-subtiles = 256 j's). Slot s = (k>>1)*4+wv
// (16 per pair) takes: uniform chunk of each group + one staircase row of
// each group (g_hi row s>>2, g_lo row 3-(s>>2)). Every wave: 40 iters,
// 272 terms/lane.
__global__ __launch_bounds__(BLK) void rank_partial_kernel(
    const float* __restrict__ preds,
    const float* __restrict__ labels,
    float* __restrict__ partial) {
  const int bid = blockIdx.x;
  const int b = bid >> 3;
  const int k = bid & 7;

  __shared__ float2 pl[S];
  __shared__ float wsum[BLK / 64];

  const float* pr = preds + (size_t)b * S;
  const float* lr = labels + (size_t)b * S;
  {
    const float4 pv = ((const float4*)pr)[threadIdx.x];
    const float4 lv = ((const float4*)lr)[threadIdx.x];
    const float pm[4] = {pv.x, pv.y, pv.z, pv.w};
    const float lm[4] = {lv.x, lv.y, lv.z, lv.w};
#pragma unroll
    for (int e = 0; e < 4; ++e) {
      float m = (lm[e] != -1.0f) ? 1.0f : 0.0f;
      pl[threadIdx.x * 4 + e] = make_float2(pm[e] * m, lm[e] * m);
    }
  }
  __syncthreads();

  const int wv = threadIdx.x >> 6;
  const int lane = threadIdx.x & 63;
  const int P = k & 1;
  const int s = (k >> 1) * 4 + wv;     // slot 0..15 within pair
  const int g_lo = P, g_hi = 3 - P;
  const float4* pl4 = (const float4*)pl;

  // j registers + masks for both groups (masked p/l from LDS, mask from global).
  float pjl[4], ljl[4], mjl[4], pjh[4], ljh[4], mjh[4];
#pragma unroll
  for (int r = 0; r < 4; ++r) {
    int jl = g_lo * 256 + r * 64 + lane;
    int jh = g_hi * 256 + r * 64 + lane;
    float2 vl = pl[jl], vh = pl[jh];
    pjl[r] = vl.x; ljl[r] = vl.y; mjl[r] = (lr[jl] != -1.0f) ? 1.0f : 0.0f;
    pjh[r] = vh.x; ljh[r] = vh.y; mjh[r] = (lr[jh] != -1.0f) ? 1.0f : 0.0f;
  }

  float accl[4] = {0.f, 0.f, 0.f, 0.f};
  float acch[4] = {0.f, 0.f, 0.f, 0.f};

  // Uniform chunks: group g needs i in [0, 256g); slot s takes 16g i's = 8g f4.
  if (g_lo > 0) uni4(pl4, s * 8 * g_lo, 8 * g_lo, pjl, ljl, accl);
  uni4(pl4, s * 8 * g_hi, 8 * g_hi, pjh, ljh, acch);

  // Staircase rows (8 f4-iters each).
  const int R = s >> 2;
  const int off = (s & 3) * 16;
  stair(pl4, g_hi * 256, R, off, lane, pjh, ljh, acch);
  stair(pl4, g_lo * 256, 3 - R, off, lane, pjl, ljl, accl);

  float wacc = 0.0f;
#pragma unroll
  for (int r = 0; r < 4; ++r) {
    wacc = fmaf(accl[r], mjl[r], wacc);
    wacc = fmaf(acch[r], mjh[r], wacc);
  }

  // Deterministic block reduction.
  for (int offr = 32; offr > 0; offr >>= 1)
    wacc += __shfl_down(wacc, offr, 64);
  if (lane == 0) wsum[wv] = wacc;
  __syncthreads();
  if (threadIdx.x == 0)
    partial[bid] = wsum[0] + wsum[1] + wsum[2] + wsum[3];
}

// Kernel 2: one wave. Lane b: two float4 loads cover its 8 partials.
__global__ __launch_bounds__(64) void rank_final_kernel(
    const float* __restrict__ partial,
    const int* __restrict__ lens,
    float* __restrict__ out,
    int B) {
  const int b = threadIdx.x;
  float norm = 0.0f, sents = 0.0f;
  if (b < B) {
    const float4* p4 = (const float4*)partial;
    float4 a = p4[b * 2];
    float4 c = p4[b * 2 + 1];
    float sum = ((a.x + a.y) + (a.z + a.w)) + ((c.x + c.y) + (c.z + c.w));
    float len = (float)lens[b];
    norm = sum / (len * len);
    sents = (lens[b] != 0) ? 1.0f : 0.0f;
  }
  for (int off = 32; off > 0; off >>= 1) {
    norm  += __shfl_down(norm, off, 64);
    sents += __shfl_down(sents, off, 64);
  }
  if (threadIdx.x == 0) {
    out[0] = norm / sents;
    out[1] = sents;
  }
}

extern "C" void kernel_launch(void* const* d_in, const int* in_sizes, int n_in,
                              void* d_out, int out_size, void* d_ws, size_t ws_size,
                              hipStream_t stream) {
  const float* preds  = (const float*)d_in[0];
  const float* labels = (const float*)d_in[1];
  const int*   lens   = (const int*)d_in[2];
  float* out = (float*)d_out;

  const int B = in_sizes[2];                  // 64
  float* partial = (float*)d_ws;              // B * 8 floats

  rank_partial_kernel<<<dim3(B * 8), dim3(BLK), 0, stream>>>(preds, labels, partial);
  rank_final_kernel<<<dim3(1), dim3(64), 0, stream>>>(partial, lens, out, B);
}

// Round 7
// 15.873 us; speedup vs baseline: 2.2108x; 1.0352x over previous
//
#include <hip/hip_runtime.h>
#include <hip/hip_bf16.h>

#define S 1024
#define BLK 256    // 4 waves; 16 blocks/batch -> 1024 blocks, 4/CU

// hinge term: relu(1 - sign(l_i-l_j)*(p_i-p_j)); tie dl==0 -> x=0 -> term=1.
__device__ __forceinline__ float pair_term(float pi, float li, float pj, float lj) {
  float dp = pi - pj;
  float dl = li - lj;
  unsigned sx = __float_as_uint(dl) & 0x80000000u;
  float x = __uint_as_float(__float_as_uint(dp) ^ sx);  // sign(dl)*dp (dl!=0)
  x = (dl == 0.0f) ? 0.0f : x;
  return fmaxf(1.0f - x, 0.0f);
}

// N4 float4-iterations starting at f4lo; all 4 regs valid. Compile-time trip.
template <int N4>
__device__ __forceinline__ void uni4(const float4* pl4, int f4lo,
                                     const float pj[4], const float lj[4],
                                     float acc[4]) {
#pragma unroll
  for (int t = 0; t < N4; ++t) {
    float4 q = pl4[f4lo + t];
#pragma unroll
    for (int r = 0; r < 4; ++r) {
      acc[r] += pair_term(q.x, q.y, pj[r], lj[r]);
      acc[r] += pair_term(q.z, q.w, pj[r], lj[r]);
    }
  }
}

// Staircase row R of the 256-wide group at gb: i in [gb+64R+off, +8) (4 f4).
// Reg R predicated (i<j), regs r>R fully valid, regs r<R excluded.
template <int R>
__device__ __forceinline__ void stair_t(const float4* pl4, int gb, int off,
                                        int lane, const float pj[4],
                                        const float lj[4], float acc[4]) {
  const int i0 = gb + 64 * R + off;
  const int j = gb + 64 * R + lane;
#pragma unroll
  for (int t = 0; t < 4; ++t) {
    float4 q = pl4[(i0 >> 1) + t];
    const int i = i0 + 2 * t;
    float ta = (i     < j) ? pair_term(q.x, q.y, pj[R], lj[R]) : 0.0f;
    float tb = (i + 1 < j) ? pair_term(q.z, q.w, pj[R], lj[R]) : 0.0f;
    acc[R] += ta + tb;
#pragma unroll
    for (int r = R + 1; r < 4; ++r) {
      acc[r] += pair_term(q.x, q.y, pj[r], lj[r]);
      acc[r] += pair_term(q.z, q.w, pj[r], lj[r]);
    }
  }
}

__device__ __forceinline__ void stair(const float4* pl4, int gb, int R, int off,
                                      int lane, const float pj[4],
                                      const float lj[4], float acc[4]) {
  switch (R) {  // wave-uniform
    case 0: stair_t<0>(pl4, gb, off, lane, pj, lj, acc); break;
    case 1: stair_t<1>(pl4, gb, off, lane, pj, lj, acc); break;
    case 2: stair_t<2>(pl4, gb, off, lane, pj, lj, acc); break;
    default: stair_t<3>(pl4, gb, off, lane, pj, lj, acc); break;
  }
}

// Body templated on group pair {GLO, 3-GLO}: all uniform-loop trips static.
// Slot s in 0..31: uniform f4 chunk [s*4*g, +4*g) of each group, plus
// staircase rows: g_hi row s>>3, g_lo row 3-(s>>3), offset (s&7)*8.
template <int GLO>
__device__ __forceinline__ float body(const float2* pl, const float4* pl4,
                                      const float* lr, int s, int lane) {
  constexpr int GHI = 3 - GLO;
  float pjl[4], ljl[4], mjl[4], pjh[4], ljh[4], mjh[4];
#pragma unroll
  for (int r = 0; r < 4; ++r) {
    int jl = GLO * 256 + r * 64 + lane;
    int jh = GHI * 256 + r * 64 + lane;
    float2 vl = pl[jl], vh = pl[jh];
    pjl[r] = vl.x; ljl[r] = vl.y; mjl[r] = (lr[jl] != -1.0f) ? 1.0f : 0.0f;
    pjh[r] = vh.x; ljh[r] = vh.y; mjh[r] = (lr[jh] != -1.0f) ? 1.0f : 0.0f;
  }

  float accl[4] = {0.f, 0.f, 0.f, 0.f};
  float acch[4] = {0.f, 0.f, 0.f, 0.f};

  if (GLO > 0) uni4<4 * GLO>(pl4, s * 4 * GLO, pjl, ljl, accl);
  uni4<4 * GHI>(pl4, s * 4 * GHI, pjh, ljh, acch);

  const int R = s >> 3;
  const int off = (s & 7) * 8;
  stair(pl4, GHI * 256, R, off, lane, pjh, ljh, acch);
  stair(pl4, GLO * 256, 3 - R, off, lane, pjl, ljl, accl);

  float wacc = 0.0f;
#pragma unroll
  for (int r = 0; r < 4; ++r) {
    wacc = fmaf(accl[r], mjl[r], wacc);
    wacc = fmaf(acch[r], mjh[r], wacc);
  }
  return wacc;
}

// Kernel 1: batch b = bid>>4, k = bid&15. P=k&1 -> pair {P,3-P};
// slot s = (k>>1)*4 + wave (0..31). Every wave ~136 terms/lane, balanced.
__global__ __launch_bounds__(BLK) void rank_partial_kernel(
    const float* __restrict__ preds,
    const float* __restrict__ labels,
    float* __restrict__ partial) {
  const int bid = blockIdx.x;
  const int b = bid >> 4;
  const int k = bid & 15;

  __shared__ float2 pl[S];
  __shared__ float wsum[BLK / 64];

  const float* pr = preds + (size_t)b * S;
  const float* lr = labels + (size_t)b * S;
  {
    const float4 pv = ((const float4*)pr)[threadIdx.x];
    const float4 lv = ((const float4*)lr)[threadIdx.x];
    const float pm[4] = {pv.x, pv.y, pv.z, pv.w};
    const float lm[4] = {lv.x, lv.y, lv.z, lv.w};
#pragma unroll
    for (int e = 0; e < 4; ++e) {
      float m = (lm[e] != -1.0f) ? 1.0f : 0.0f;
      pl[threadIdx.x * 4 + e] = make_float2(pm[e] * m, lm[e] * m);
    }
  }
  __syncthreads();

  const int wv = threadIdx.x >> 6;
  const int lane = threadIdx.x & 63;
  const int s = (k >> 1) * 4 + wv;
  const float4* pl4 = (const float4*)pl;

  float wacc = (k & 1) ? body<1>(pl, pl4, lr, s, lane)
                       : body<0>(pl, pl4, lr, s, lane);

  for (int offr = 32; offr > 0; offr >>= 1)
    wacc += __shfl_down(wacc, offr, 64);
  if (lane == 0) wsum[wv] = wacc;
  __syncthreads();
  if (threadIdx.x == 0)
    partial[bid] = wsum[0] + wsum[1] + wsum[2] + wsum[3];
}

// Kernel 2: one wave. Lane b sums its 16 partials (4 float4 loads).
__global__ __launch_bounds__(64) void rank_final_kernel(
    const float* __restrict__ partial,
    const int* __restrict__ lens,
    float* __restrict__ out,
    int B) {
  const int b = threadIdx.x;
  float norm = 0.0f, sents = 0.0f;
  if (b < B) {
    const float4* p4 = (const float4*)partial;
    float sum = 0.0f;
#pragma unroll
    for (int q = 0; q < 4; ++q) {
      float4 a = p4[b * 4 + q];
      sum += (a.x + a.y) + (a.z + a.w);
    }
    float len = (float)lens[b];
    norm = sum / (len * len);
    sents = (lens[b] != 0) ? 1.0f : 0.0f;
  }
  for (int off = 32; off > 0; off >>= 1) {
    norm  += __shfl_down(norm, off, 64);
    sents += __shfl_down(sents, off, 64);
  }
  if (threadIdx.x == 0) {
    out[0] = norm / sents;
    out[1] = sents;
  }
}

extern "C" void kernel_launch(void* const* d_in, const int* in_sizes, int n_in,
                              void* d_out, int out_size, void* d_ws, size_t ws_size,
                              hipStream_t stream) {
  const float* preds  = (const float*)d_in[0];
  const float* labels = (const float*)d_in[1];
  const int*   lens   = (const int*)d_in[2];
  float* out = (float*)d_out;

  const int B = in_sizes[2];                  // 64
  float* partial = (float*)d_ws;              // B * 16 floats

  rank_partial_kernel<<<dim3(B * 16), dim3(BLK), 0, stream>>>(preds, labels, partial);
  rank_final_kernel<<<dim3(1), dim3(64), 0, stream>>>(partial, lens, out, B);
}

// Round 8
// 13.533 us; speedup vs baseline: 2.5930x; 1.1729x over previous
//
#include <hip/hip_runtime.h>
#include <hip/hip_bf16.h>

#define S 1024
#define BLK 256    // 4 waves; 16 blocks/batch -> 1024 blocks, 4/CU

// hinge term: relu(1 - sign(l_i-l_j)*(p_i-p_j)), tie dl==0 -> 1.
// Labels are integer-valued (masked to {0..49}), so dl is an exact integer
// and sign(dl) == clamp(dl,-1,1) == v_med3_f32(dl,-1,1): 1 instruction.
// fma(-c,dp,1) is exact-product fma -> bit-identical to np's mul+sub.
// 6 VALU/term: sub, sub, med3, fma, max, (+acc add at caller).
__device__ __forceinline__ float pair_term(float pi, float li, float pj, float lj) {
  float dp = pi - pj;
  float dl = li - lj;
  float c = fminf(fmaxf(dl, -1.0f), 1.0f);   // v_med3_f32 clamp idiom
  return fmaxf(fmaf(-c, dp, 1.0f), 0.0f);
}

// N4 float4-iterations starting at f4lo; all 4 regs valid. Compile-time trip.
template <int N4>
__device__ __forceinline__ void uni4(const float4* pl4, int f4lo,
                                     const float pj[4], const float lj[4],
                                     float acc[4]) {
#pragma unroll
  for (int t = 0; t < N4; ++t) {
    float4 q = pl4[f4lo + t];
#pragma unroll
    for (int r = 0; r < 4; ++r) {
      acc[r] += pair_term(q.x, q.y, pj[r], lj[r]);
      acc[r] += pair_term(q.z, q.w, pj[r], lj[r]);
    }
  }
}

// Staircase row R of the 256-wide group at gb: i in [gb+64R+off, +8) (4 f4).
// Reg R predicated (i<j), regs r>R fully valid, regs r<R excluded.
template <int R>
__device__ __forceinline__ void stair_t(const float4* pl4, int gb, int off,
                                        int lane, const float pj[4],
                                        const float lj[4], float acc[4]) {
  const int i0 = gb + 64 * R + off;
  const int j = gb + 64 * R + lane;
#pragma unroll
  for (int t = 0; t < 4; ++t) {
    float4 q = pl4[(i0 >> 1) + t];
    const int i = i0 + 2 * t;
    float ta = (i     < j) ? pair_term(q.x, q.y, pj[R], lj[R]) : 0.0f;
    float tb = (i + 1 < j) ? pair_term(q.z, q.w, pj[R], lj[R]) : 0.0f;
    acc[R] += ta + tb;
#pragma unroll
    for (int r = R + 1; r < 4; ++r) {
      acc[r] += pair_term(q.x, q.y, pj[r], lj[r]);
      acc[r] += pair_term(q.z, q.w, pj[r], lj[r]);
    }
  }
}

__device__ __forceinline__ void stair(const float4* pl4, int gb, int R, int off,
                                      int lane, const float pj[4],
                                      const float lj[4], float acc[4]) {
  switch (R) {  // wave-uniform
    case 0: stair_t<0>(pl4, gb, off, lane, pj, lj, acc); break;
    case 1: stair_t<1>(pl4, gb, off, lane, pj, lj, acc); break;
    case 2: stair_t<2>(pl4, gb, off, lane, pj, lj, acc); break;
    default: stair_t<3>(pl4, gb, off, lane, pj, lj, acc); break;
  }
}

// Body templated on group pair {GLO, 3-GLO}: all uniform-loop trips static.
// Slot s in 0..31: uniform f4 chunk [s*4*g, +4*g) of each group, plus
// staircase rows: g_hi row s>>3, g_lo row 3-(s>>3), offset (s&7)*8.
template <int GLO>
__device__ __forceinline__ float body(const float2* pl, const float4* pl4,
                                      const float* msk, int s, int lane) {
  constexpr int GHI = 3 - GLO;
  float pjl[4], ljl[4], mjl[4], pjh[4], ljh[4], mjh[4];
#pragma unroll
  for (int r = 0; r < 4; ++r) {
    int jl = GLO * 256 + r * 64 + lane;
    int jh = GHI * 256 + r * 64 + lane;
    float2 vl = pl[jl], vh = pl[jh];
    pjl[r] = vl.x; ljl[r] = vl.y; mjl[r] = msk[jl];
    pjh[r] = vh.x; ljh[r] = vh.y; mjh[r] = msk[jh];
  }

  float accl[4] = {0.f, 0.f, 0.f, 0.f};
  float acch[4] = {0.f, 0.f, 0.f, 0.f};

  if (GLO > 0) uni4<4 * GLO>(pl4, s * 4 * GLO, pjl, ljl, accl);
  uni4<4 * GHI>(pl4, s * 4 * GHI, pjh, ljh, acch);

  const int R = s >> 3;
  const int off = (s & 7) * 8;
  stair(pl4, GHI * 256, R, off, lane, pjh, ljh, acch);
  stair(pl4, GLO * 256, 3 - R, off, lane, pjl, ljl, accl);

  float wacc = 0.0f;
#pragma unroll
  for (int r = 0; r < 4; ++r) {
    wacc = fmaf(accl[r], mjl[r], wacc);
    wacc = fmaf(acch[r], mjh[r], wacc);
  }
  return wacc;
}

// Kernel 1: batch b = bid>>4, k = bid&15. P=k&1 -> pair {P,3-P};
// slot s = (k>>1)*4 + wave (0..31). Every wave ~136 terms/lane, balanced.
__global__ __launch_bounds__(BLK) void rank_partial_kernel(
    const float* __restrict__ preds,
    const float* __restrict__ labels,
    float* __restrict__ partial) {
  const int bid = blockIdx.x;
  const int b = bid >> 4;
  const int k = bid & 15;

  __shared__ float2 pl[S];
  __shared__ float msk[S];
  __shared__ float wsum[BLK / 64];

  const float* pr = preds + (size_t)b * S;
  const float* lr = labels + (size_t)b * S;
  {
    const float4 pv = ((const float4*)pr)[threadIdx.x];
    const float4 lv = ((const float4*)lr)[threadIdx.x];
    const float pm[4] = {pv.x, pv.y, pv.z, pv.w};
    const float lm[4] = {lv.x, lv.y, lv.z, lv.w};
#pragma unroll
    for (int e = 0; e < 4; ++e) {
      float m = (lm[e] != -1.0f) ? 1.0f : 0.0f;
      pl[threadIdx.x * 4 + e] = make_float2(pm[e] * m, lm[e] * m);
      msk[threadIdx.x * 4 + e] = m;
    }
  }
  __syncthreads();

  const int wv = threadIdx.x >> 6;
  const int lane = threadIdx.x & 63;
  const int s = (k >> 1) * 4 + wv;
  const float4* pl4 = (const float4*)pl;

  float wacc = (k & 1) ? body<1>(pl, pl4, msk, s, lane)
                       : body<0>(pl, pl4, msk, s, lane);

  for (int offr = 32; offr > 0; offr >>= 1)
    wacc += __shfl_down(wacc, offr, 64);
  if (lane == 0) wsum[wv] = wacc;
  __syncthreads();
  if (threadIdx.x == 0)
    partial[bid] = wsum[0] + wsum[1] + wsum[2] + wsum[3];
}

// Kernel 2: one wave. Lane b sums its 16 partials (4 float4 loads).
__global__ __launch_bounds__(64) void rank_final_kernel(
    const float* __restrict__ partial,
    const int* __restrict__ lens,
    float* __restrict__ out,
    int B) {
  const int b = threadIdx.x;
  float norm = 0.0f, sents = 0.0f;
  if (b < B) {
    const float4* p4 = (const float4*)partial;
    float sum = 0.0f;
#pragma unroll
    for (int q = 0; q < 4; ++q) {
      float4 a = p4[b * 4 + q];
      sum += (a.x + a.y) + (a.z + a.w);
    }
    float len = (float)lens[b];
    norm = sum / (len * len);
    sents = (lens[b] != 0) ? 1.0f : 0.0f;
  }
  for (int off = 32; off > 0; off >>= 1) {
    norm  += __shfl_down(norm, off, 64);
    sents += __shfl_down(sents, off, 64);
  }
  if (threadIdx.x == 0) {
    out[0] = norm / sents;
    out[1] = sents;
  }
}

extern "C" void kernel_launch(void* const* d_in, const int* in_sizes, int n_in,
                              void* d_out, int out_size, void* d_ws, size_t ws_size,
                              hipStream_t stream) {
  const float* preds  = (const float*)d_in[0];
  const float* labels = (const float*)d_in[1];
  const int*   lens   = (const int*)d_in[2];
  float* out = (float*)d_out;

  const int B = in_sizes[2];                  // 64
  float* partial = (float*)d_ws;              // B * 16 floats

  rank_partial_kernel<<<dim3(B * 16), dim3(BLK), 0, stream>>>(preds, labels, partial);
  rank_final_kernel<<<dim3(1), dim3(64), 0, stream>>>(partial, lens, out, B);
}